// Round 1
// baseline (807.301 us; speedup 1.0000x reference)
//
#include <hip/hip_runtime.h>
#include <math.h>

#define NN   1536
#define DG   32
#define BB   8
#define OBSD 33
#define HID  64
#define NHEAD 4
#define CCH  8
#define EE   (NN*DG)   // 49152

__device__ __forceinline__ float sigm(float x){ return 1.0f/(1.0f+expf(-x)); }

// ---------------- K0: ObsEmbedding for all (B,N) ----------------
// block=64: wave handles 2 (b,n) nodes, 32 lanes each. width-32 shuffles.
__global__ void k_emb(const float* __restrict__ Ht,
                      const float* __restrict__ We1, const float* __restrict__ be1,
                      const float* __restrict__ We2, const float* __restrict__ be2,
                      const float* __restrict__ lng, const float* __restrict__ lnb,
                      float* __restrict__ Hemb){
    int lane = threadIdx.x;              // 0..63
    int j = lane & 31;
    int bn = blockIdx.x*2 + (lane>>5);   // 0 .. B*N-1
    const float* hrow = Ht + (size_t)bn*OBSD;
    float x1 = be1[j];
    for(int o=0;o<OBSD;o++) x1 += hrow[o]*We1[o*32+j];
    x1 = fmaxf(x1,0.f);
    float x2 = be2[j];
    for(int i=0;i<32;i++){
        float xi = __shfl(x1, (lane & 32) | i, 64);
        x2 += xi * We2[i*32+j];
    }
    x2 = fmaxf(x2,0.f);
    float mu = x2;
    for(int m=16;m>=1;m>>=1) mu += __shfl_xor(mu, m, 32);
    mu *= (1.0f/32.0f);
    float d = x2-mu; float var = d*d;
    for(int m=16;m>=1;m>>=1) var += __shfl_xor(var, m, 32);
    var *= (1.0f/32.0f);
    Hemb[(size_t)bn*32 + j] = d*rsqrtf(var+1e-5f)*lng[j]+lnb[j];
}

// ---------------- CSR build (dst is constant across steps) ----------------
__global__ void k_count(const int* __restrict__ dst, int* __restrict__ cursor){
    int e = blockIdx.x*256+threadIdx.x;
    if(e<EE) atomicAdd(&cursor[dst[e]],1);
}
__global__ void k_scan(int* __restrict__ cnt, int* __restrict__ indptr){
    __shared__ int part[256];
    int t = threadIdx.x;
    int local[6]; int s=0;
    for(int i=0;i<6;i++){ local[i]=cnt[t*6+i]; s+=local[i]; }
    part[t]=s; __syncthreads();
    if(t==0){ int acc=0; for(int i=0;i<256;i++){ int v=part[i]; part[i]=acc; acc+=v; } }
    __syncthreads();
    int pre = part[t];
    for(int i=0;i<6;i++){ int idx=t*6+i; indptr[idx]=pre; cnt[idx]=pre; pre+=local[i]; }
    if(t==255) indptr[NN]=EE;
}
__global__ void k_fill(const int* __restrict__ dst, int* __restrict__ cursor, int* __restrict__ eids){
    int e = blockIdx.x*256+threadIdx.x;
    if(e<EE){ int p = atomicAdd(&cursor[dst[e]],1); eids[p]=e; }
}

// ---------------- K1: per-node GRU + P,Q (edge scorer halves) + xh + a_s,a_d ----------------
// block=64 = one node. Cross-lane via shuffles, no LDS.
__global__ void k_node(const float* __restrict__ Hemb, int t,
                       const float* __restrict__ Wih, const float* __restrict__ Whh,
                       const float* __restrict__ bih, const float* __restrict__ bhh,
                       const float* __restrict__ Ws1, const float* __restrict__ Wgat,
                       const float* __restrict__ atts, const float* __restrict__ attd,
                       float* __restrict__ h, float* __restrict__ P, float* __restrict__ Q,
                       float* __restrict__ xh, float* __restrict__ as_, float* __restrict__ ad_){
    int n = blockIdx.x; int j = threadIdx.x;  // 0..63
    float hold = h[n*HID+j];
    float ev = (j<32) ? Hemb[((size_t)t*NN + n)*32 + j] : 0.f;
    float gr=0.f, gz=0.f, gn=0.f;
    for(int kk=0;kk<32;kk++){
        float ek = __shfl(ev,kk);
        gr += ek*Wih[j*32+kk];
        gz += ek*Wih[(64+j)*32+kk];
        gn += ek*Wih[(128+j)*32+kk];
    }
    float hr=0.f,hz=0.f,hn=0.f;
    for(int kk=0;kk<64;kk++){
        float hk = __shfl(hold,kk);
        hr += hk*Whh[j*64+kk];
        hz += hk*Whh[(64+j)*64+kk];
        hn += hk*Whh[(128+j)*64+kk];
    }
    float r  = sigm(gr+bih[j]     + hr+bhh[j]);
    float z  = sigm(gz+bih[64+j]  + hz+bhh[64+j]);
    float nn_= tanhf(gn+bih[128+j] + r*(hn+bhh[128+j]));
    float hnew = (1.f-z)*nn_ + z*hold;
    h[n*HID+j]=hnew;
    float p=0.f,q=0.f,xv=0.f;
    for(int kk=0;kk<64;kk++){
        float hk=__shfl(hnew,kk);
        p += hk*Ws1[kk*64+j];
        q += hk*Ws1[(64+kk)*64+j];
        if(j<32) xv += hk*Wgat[kk*32+j];
    }
    P[n*64+j]=p; Q[n*64+j]=q;
    if(j<32){
        xh[n*32+j]=xv;
        float asv = xv*atts[j];
        float adv = xv*attd[j];
        for(int m=1;m<8;m<<=1){ asv += __shfl_xor(asv,m); adv += __shfl_xor(adv,m); }
        if((j&7)==0){ as_[n*4+(j>>3)]=asv; ad_[n*4+(j>>3)]=adv; }
    }
}

// ---------------- K2: edge scores + per-source-row top-k -> w ----------------
// block=64: two source rows per wave, 32 lanes each (one edge per lane).
__global__ void k_edge(const float* __restrict__ P, const float* __restrict__ Q,
                       const float* __restrict__ bs1, const float* __restrict__ Ws2,
                       const float* __restrict__ bs2, const int* __restrict__ dst,
                       const int* __restrict__ kptr, float* __restrict__ w){
    int lane = threadIdx.x;
    int row = blockIdx.x*2 + (lane>>5);
    int d = lane & 31;
    int e = row*DG + d;
    int de = dst[e];
    const float* Pr = P + row*64;
    const float* Qr = Q + de*64;
    float acc = 0.f;
    for(int j=0;j<64;j++){
        float tv = Pr[j]+Qr[j]+bs1[j];
        tv = fmaxf(tv,0.f);
        acc += tv*Ws2[j];
    }
    float score = sigm(acc + bs2[0]);
    int kk = kptr[0]; if(kk>32) kk=32; if(kk<0) kk=0;
    bool sel=false;
    for(int it=0; it<kk; it++){
        float v = sel ? -INFINITY : score;
        int idx = d;
        for(int m=16;m>=1;m>>=1){
            float ov = __shfl_xor(v,m,32);
            int   oi = __shfl_xor(idx,m,32);
            if(ov>v || (ov==v && oi<idx)){ v=ov; idx=oi; }  // top_k tie-break: lowest index
        }
        if(idx==d) sel=true;
    }
    w[e] = sel ? score : 0.f;
}

// ---------------- K3: per-dst masked softmax + message aggregation ----------------
// block=256 = 4 waves, wave = head. CSR edge list per dst node.
__global__ void __launch_bounds__(256) k_soft(const int* __restrict__ indptr, const int* __restrict__ eids,
                       const int* __restrict__ src,
                       const float* __restrict__ as_, const float* __restrict__ ad_,
                       const float* __restrict__ w, const float* __restrict__ xhb,
                       const float* __restrict__ bgat,
                       float* __restrict__ alpha, float* __restrict__ outp, int t){
    int n = blockIdx.x;
    int h = threadIdx.x>>6;
    int lane = threadIdx.x&63;
    int beg = indptr[n], end = indptr[n+1];
    float adv = ad_[n*4+h];
    float m = -INFINITY;
    for(int i=beg+lane;i<end;i+=64){
        int e = eids[i];
        if(w[e]>0.f){
            float lg = as_[src[e]*4+h]+adv;
            lg = lg>0.f ? lg : 0.2f*lg;
            m = fmaxf(m,lg);
        }
    }
    for(int mm=32;mm>=1;mm>>=1) m = fmaxf(m,__shfl_xor(m,mm));
    float ssum=0.f;
    for(int i=beg+lane;i<end;i+=64){
        int e = eids[i];
        float ex = 0.f;
        if(w[e]>0.f){
            float lg = as_[src[e]*4+h]+adv;
            lg = lg>0.f ? lg : 0.2f*lg;
            ex = expf(lg-m);
        }
        alpha[e*4+h]=ex;
        ssum += ex;
    }
    for(int mm=32;mm>=1;mm>>=1) ssum += __shfl_xor(ssum,mm);
    float inv = 1.0f/fmaxf(ssum,1e-16f);
    float acc[8];
    #pragma unroll
    for(int c=0;c<8;c++) acc[c]=0.f;
    for(int i=beg+lane;i<end;i+=64){
        int e = eids[i];
        float a = alpha[e*4+h]*inv;
        alpha[e*4+h]=a;
        if(a>0.f){
            float aw = a*w[e];
            const float* xr = xhb + src[e]*32 + h*8;
            #pragma unroll
            for(int c=0;c<8;c++) acc[c] += aw*xr[c];
        }
    }
    for(int mm=32;mm>=1;mm>>=1){
        #pragma unroll
        for(int c=0;c<8;c++) acc[c] += __shfl_xor(acc[c],mm);
    }
    if(lane==0){
        float* o = outp + ((size_t)t*NN+n)*32 + h*8;
        #pragma unroll
        for(int c=0;c<8;c++) o[c] = acc[c] + bgat[h*8+c];
    }
}

// ---------------- K4: per-source-row normalize + dense A row write ----------------
// One block per (t, src_row): builds 4 head-rows (NN floats each) in LDS, streams out.
// Replaces a 302 MB global memset + global atomics.
__global__ void __launch_bounds__(256) k_scatter(const float* __restrict__ alpha,
                       const int* __restrict__ dst, float* __restrict__ attn, int t){
    __shared__ float rowbuf[NHEAD][NN];
    __shared__ float rs[NHEAD];
    __shared__ float rsf[NHEAD];
    int n = blockIdx.x;
    int tid = threadIdx.x;
    for(int i=tid;i<NHEAD*NN;i+=256) ((float*)rowbuf)[i]=0.f;
    if(tid<NHEAD) rs[tid]=0.f;
    __syncthreads();
    float a=0.f; int de=0; int h=0;
    if(tid<128){
        int d = tid>>2; h = tid&3;
        int e = n*DG+d;
        a = alpha[e*4+h];
        de = dst[e];
        if(a>0.f) atomicAdd(&rs[h], a);
    }
    __syncthreads();
    if(tid<NHEAD) rsf[tid] = 1.0f/fmaxf(rs[tid],1e-9f);
    __syncthreads();
    if(tid<128 && a>0.f) atomicAdd(&rowbuf[h][de], a*rsf[h]);
    __syncthreads();
    size_t tb = (size_t)t*NHEAD*NN*NN;
    for(int i=tid;i<NHEAD*(NN/4);i+=256){
        int hh = i/(NN/4); int c4 = i%(NN/4);
        float4 v = ((const float4*)rowbuf[hh])[c4];
        ((float4*)(attn + tb + (size_t)hh*NN*NN + (size_t)n*NN))[c4] = v;
    }
}

extern "C" void kernel_launch(void* const* d_in, const int* in_sizes, int n_in,
                              void* d_out, int out_size, void* d_ws, size_t ws_size,
                              hipStream_t stream) {
    const float* Ht   = (const float*)d_in[0];
    const int*   src  = (const int*)  d_in[1];
    const int*   dst  = (const int*)  d_in[2];
    const int*   kptr = (const int*)  d_in[3];
    const float* We1  = (const float*)d_in[4];
    const float* be1  = (const float*)d_in[5];
    const float* We2  = (const float*)d_in[6];
    const float* be2  = (const float*)d_in[7];
    const float* lng  = (const float*)d_in[8];
    const float* lnb  = (const float*)d_in[9];
    const float* Wih  = (const float*)d_in[10];
    const float* Whh  = (const float*)d_in[11];
    const float* bih  = (const float*)d_in[12];
    const float* bhh  = (const float*)d_in[13];
    const float* Ws1  = (const float*)d_in[14];
    const float* bs1  = (const float*)d_in[15];
    const float* Ws2  = (const float*)d_in[16];
    const float* bs2  = (const float*)d_in[17];
    const float* Wgat = (const float*)d_in[18];
    const float* atts = (const float*)d_in[19];
    const float* attd = (const float*)d_in[20];
    const float* bgat = (const float*)d_in[21];

    float* outp = (float*)d_out;                       // (B,N,32)
    float* attn = outp + (size_t)BB*NN*32;             // (B,HEADS,N,N)

    // workspace layout (floats); total ~4.2 MB
    float* ws    = (float*)d_ws;
    float* Hemb  = ws;                   // 393216
    float* h     = ws + 393216;          // 98304
    float* P     = ws + 491520;          // 98304
    float* Q     = ws + 589824;          // 98304
    float* xh    = ws + 688128;          // 49152
    float* as_   = ws + 737280;          // 6144
    float* ad_   = ws + 743424;          // 6144
    float* wbuf  = ws + 749568;          // 49152
    float* alpha = ws + 798720;          // 196608
    int*   ibase = (int*)(ws + 995328);
    int*   cursor= ibase;                // NN
    int*   indptr= ibase + 2048;         // NN+1
    int*   eids  = ibase + 4096;         // EE

    hipMemsetAsync(h, 0, (size_t)NN*HID*sizeof(float), stream);       // h0 = zeros
    hipMemsetAsync(cursor, 0, (size_t)NN*sizeof(int), stream);

    k_emb<<<BB*NN/2, 64, 0, stream>>>(Ht, We1, be1, We2, be2, lng, lnb, Hemb);
    k_count<<<EE/256, 256, 0, stream>>>(dst, cursor);
    k_scan<<<1, 256, 0, stream>>>(cursor, indptr);
    k_fill<<<EE/256, 256, 0, stream>>>(dst, cursor, eids);

    for(int t=0;t<BB;t++){
        k_node<<<NN, 64, 0, stream>>>(Hemb, t, Wih, Whh, bih, bhh, Ws1, Wgat, atts, attd,
                                      h, P, Q, xh, as_, ad_);
        k_edge<<<NN/2, 64, 0, stream>>>(P, Q, bs1, Ws2, bs2, dst, kptr, wbuf);
        k_soft<<<NN, 256, 0, stream>>>(indptr, eids, src, as_, ad_, wbuf, xh, bgat,
                                       alpha, outp, t);
        k_scatter<<<NN, 256, 0, stream>>>(alpha, dst, attn, t);
    }
}

// Round 2
// 521.720 us; speedup vs baseline: 1.5474x; 1.5474x over previous
//
#include <hip/hip_runtime.h>
#include <math.h>

#define NN   1536
#define DG   32
#define BB   8
#define OBSD 33
#define HID  64
#define NHEAD 4
#define EE   (NN*DG)   // 49152

__device__ __forceinline__ float sigm(float x){ return 1.0f/(1.0f+expf(-x)); }

// ---------------- K0: ObsEmbedding + GRU input transform, all (B,N) ----------------
// block=256 = 4 waves, wave = one (t,n) node (lanes duplicated in halves for emb phase).
// GI[bn][0..191] = e@Wih.T + bih  (h-independent part of the GRU, hoisted out of the
// serial chain). Wih staged in LDS pad-33 to avoid stride-32 line/bank divergence.
__global__ void __launch_bounds__(256) k_embgi(
                      const float* __restrict__ Ht,
                      const float* __restrict__ We1, const float* __restrict__ be1,
                      const float* __restrict__ We2, const float* __restrict__ be2,
                      const float* __restrict__ lng, const float* __restrict__ lnb,
                      const float* __restrict__ Wih, const float* __restrict__ bih,
                      float* __restrict__ GI){
    __shared__ float lwih[192*33];
    int tid = threadIdx.x;
    for(int i=tid;i<192*32;i+=256){ int r=i>>5, c=i&31; lwih[r*33+c]=Wih[i]; }
    __syncthreads();
    int lane = tid & 63;
    int j32 = lane & 31;
    int bn = blockIdx.x*4 + (tid>>6);       // 0 .. B*N-1  (t-major)
    const float* hrow = Ht + (size_t)bn*OBSD;
    // layer 1 (33->32) + relu
    float x1 = be1[j32];
    for(int o=0;o<OBSD;o++) x1 += hrow[o]*We1[o*32+j32];
    x1 = fmaxf(x1,0.f);
    // layer 2 (32->32) + relu   (halves of the wave hold duplicate copies)
    float x2 = be2[j32];
    for(int i=0;i<32;i++){
        float xi = __shfl(x1, (lane & 32) | i, 64);
        x2 += xi * We2[i*32+j32];
    }
    x2 = fmaxf(x2,0.f);
    // layernorm over 32
    float mu = x2;
    for(int m=16;m>=1;m>>=1) mu += __shfl_xor(mu, m, 32);
    mu *= (1.0f/32.0f);
    float d = x2-mu; float var = d*d;
    for(int m=16;m>=1;m>>=1) var += __shfl_xor(var, m, 32);
    var *= (1.0f/32.0f);
    float xln = d*rsqrtf(var+1e-5f)*lng[j32]+lnb[j32];
    // gi = e @ Wih.T + bih   (all 64 lanes, lane j = hidden dim)
    int j = lane;
    float gr=bih[j], gz=bih[64+j], gn=bih[128+j];
    for(int kk=0;kk<32;kk++){
        float ek = __shfl(xln, kk, 64);
        gr += ek*lwih[j*33+kk];
        gz += ek*lwih[(64+j)*33+kk];
        gn += ek*lwih[(128+j)*33+kk];
    }
    float* g = GI + (size_t)bn*192;
    g[j]=gr; g[64+j]=gz; g[128+j]=gn;
}

// ---------------- CSR build (dst is constant across steps) ----------------
__global__ void k_count(const int* __restrict__ dst, int* __restrict__ cursor){
    int e = blockIdx.x*256+threadIdx.x;
    if(e<EE) atomicAdd(&cursor[dst[e]],1);
}
__global__ void k_scan(int* __restrict__ cnt, int* __restrict__ indptr){
    __shared__ int part[256];
    int t = threadIdx.x;
    int local[6]; int s=0;
    for(int i=0;i<6;i++){ local[i]=cnt[t*6+i]; s+=local[i]; }
    part[t]=s; __syncthreads();
    if(t==0){ int acc=0; for(int i=0;i<256;i++){ int v=part[i]; part[i]=acc; acc+=v; } }
    __syncthreads();
    int pre = part[t];
    for(int i=0;i<6;i++){ int idx=t*6+i; indptr[idx]=pre; cnt[idx]=pre; pre+=local[i]; }
    if(t==255) indptr[NN]=EE;
}
__global__ void k_fill(const int* __restrict__ dst, int* __restrict__ cursor, int* __restrict__ eids){
    int e = blockIdx.x*256+threadIdx.x;
    if(e<EE){ int p = atomicAdd(&cursor[dst[e]],1); eids[p]=e; }
}

// ---------------- K1: ALL 8 GRU steps in one dispatch ----------------
// Recurrence is node-local: h stays in registers across t. 6 nodes/block (384 thr),
// Whh staged once in LDS (pad-65 rows -> conflict-free stride-65 reads).
__global__ void __launch_bounds__(384) k_gru_all(const float* __restrict__ GI,
                       const float* __restrict__ Whh, const float* __restrict__ bhh,
                       float* __restrict__ Hall){
    __shared__ float lw[192*65];
    int tid = threadIdx.x;
    for(int i=tid;i<192*64;i+=384){ int r=i>>6, c=i&63; lw[r*65+c]=Whh[i]; }
    __syncthreads();
    int node = blockIdx.x*6 + (tid>>6);
    int j = tid&63;
    float b_r=bhh[j], b_z=bhh[64+j], b_n=bhh[128+j];
    const float* lwr = lw + j*65;
    const float* lwz = lw + (64+j)*65;
    const float* lwn = lw + (128+j)*65;
    float hold = 0.f;                       // h0 = zeros
    for(int t=0;t<BB;t++){
        float hr=b_r, hz=b_z, hn=b_n;
        for(int kk=0;kk<64;kk++){
            float hk = __shfl(hold,kk);
            hr += hk*lwr[kk];
            hz += hk*lwz[kk];
            hn += hk*lwn[kk];
        }
        const float* g = GI + ((size_t)t*NN+node)*192;
        float r  = sigm(g[j]     + hr);
        float z  = sigm(g[64+j]  + hz);
        float nn_= tanhf(g[128+j] + r*hn);
        hold = (1.f-z)*nn_ + z*hold;
        Hall[((size_t)t*NN+node)*64 + j] = hold;
    }
}

// ---------------- K2: per-(t,n) P,Q (edge scorer halves) + xh + a_s,a_d ----------------
// 4 nodes/block; Ws1 (32KB) + Wgat (8KB) staged in LDS (stride-1 reads, conflict-free).
__global__ void __launch_bounds__(256) k_post(const float* __restrict__ Hall,
                       const float* __restrict__ Ws1, const float* __restrict__ Wgat,
                       const float* __restrict__ atts, const float* __restrict__ attd,
                       float* __restrict__ P, float* __restrict__ Q,
                       float* __restrict__ xh, float* __restrict__ as_, float* __restrict__ ad_){
    __shared__ float ws1l[128*64];
    __shared__ float wgl[64*32];
    int tid = threadIdx.x;
    for(int i=tid;i<128*64;i+=256) ws1l[i]=Ws1[i];
    for(int i=tid;i<64*32;i+=256)  wgl[i]=Wgat[i];
    __syncthreads();
    int bn = blockIdx.x*4 + (tid>>6);
    int j = tid&63;
    float hv = Hall[(size_t)bn*64+j];
    float p=0.f,q=0.f,xv=0.f;
    for(int kk=0;kk<64;kk++){
        float hk=__shfl(hv,kk);
        p += hk*ws1l[kk*64+j];
        q += hk*ws1l[(64+kk)*64+j];
        if(j<32) xv += hk*wgl[kk*32+j];
    }
    P[(size_t)bn*64+j]=p; Q[(size_t)bn*64+j]=q;
    if(j<32){
        xh[(size_t)bn*32+j]=xv;
        float asv = xv*atts[j];
        float adv = xv*attd[j];
        for(int m=1;m<8;m<<=1){ asv += __shfl_xor(asv,m); adv += __shfl_xor(adv,m); }
        if((j&7)==0){ as_[(size_t)bn*4+(j>>3)]=asv; ad_[(size_t)bn*4+(j>>3)]=adv; }
    }
}

// ---------------- K3: edge scores + per-source-row top-k -> w, all t ----------------
// grid (768, 8): two source rows per wave, lane = edge. float4 j-loop.
__global__ void k_edge(const float* __restrict__ P, const float* __restrict__ Q,
                       const float* __restrict__ bs1, const float* __restrict__ Ws2,
                       const float* __restrict__ bs2, const int* __restrict__ dst,
                       const int* __restrict__ kptr, float* __restrict__ wbuf){
    int lane = threadIdx.x;
    int t = blockIdx.y;
    int row = blockIdx.x*2 + (lane>>5);
    int d = lane & 31;
    int e = row*DG + d;
    int de = dst[e];
    const float4* Pr = (const float4*)(P + ((size_t)t*NN+row)*64);
    const float4* Qr = (const float4*)(Q + ((size_t)t*NN+de)*64);
    const float4* B1 = (const float4*)bs1;
    const float4* W2 = (const float4*)Ws2;
    float acc = 0.f;
    #pragma unroll
    for(int jj=0;jj<16;jj++){
        float4 pv=Pr[jj], qv=Qr[jj], bv=B1[jj], wv=W2[jj];
        acc += fmaxf(pv.x+qv.x+bv.x,0.f)*wv.x;
        acc += fmaxf(pv.y+qv.y+bv.y,0.f)*wv.y;
        acc += fmaxf(pv.z+qv.z+bv.z,0.f)*wv.z;
        acc += fmaxf(pv.w+qv.w+bv.w,0.f)*wv.w;
    }
    float score = sigm(acc + bs2[0]);
    int kk = kptr[0]; if(kk>32) kk=32; if(kk<0) kk=0;
    bool sel=false;
    for(int it=0; it<kk; it++){
        float v = sel ? -INFINITY : score;
        int idx = d;
        for(int m=16;m>=1;m>>=1){
            float ov = __shfl_xor(v,m,32);
            int   oi = __shfl_xor(idx,m,32);
            if(ov>v || (ov==v && oi<idx)){ v=ov; idx=oi; }  // top_k tie-break: lowest index
        }
        if(idx==d) sel=true;
    }
    wbuf[(size_t)t*EE + e] = sel ? score : 0.f;
}

// ---------------- K4: per-dst masked softmax + message aggregation, all t ----------------
// grid (NN, 8), block=256 = 4 waves, wave = head. CSR edge list per dst node.
__global__ void __launch_bounds__(256) k_soft(const int* __restrict__ indptr, const int* __restrict__ eids,
                       const int* __restrict__ src,
                       const float* __restrict__ as_, const float* __restrict__ ad_,
                       const float* __restrict__ wbuf, const float* __restrict__ xhb,
                       const float* __restrict__ bgat,
                       float* __restrict__ alphab, float* __restrict__ outp){
    int n = blockIdx.x;
    int t = blockIdx.y;
    int h = threadIdx.x>>6;
    int lane = threadIdx.x&63;
    const float* w     = wbuf  + (size_t)t*EE;
    const float* asb   = as_   + (size_t)t*NN*4;
    const float* xhbt  = xhb   + (size_t)t*NN*32;
    float*       alpha = alphab+ (size_t)t*EE*4;
    int beg = indptr[n], end = indptr[n+1];
    float adv = ad_[((size_t)t*NN+n)*4+h];
    float m = -INFINITY;
    for(int i=beg+lane;i<end;i+=64){
        int e = eids[i];
        if(w[e]>0.f){
            float lg = asb[src[e]*4+h]+adv;
            lg = lg>0.f ? lg : 0.2f*lg;
            m = fmaxf(m,lg);
        }
    }
    for(int mm=32;mm>=1;mm>>=1) m = fmaxf(m,__shfl_xor(m,mm));
    float ssum=0.f;
    for(int i=beg+lane;i<end;i+=64){
        int e = eids[i];
        float ex = 0.f;
        if(w[e]>0.f){
            float lg = asb[src[e]*4+h]+adv;
            lg = lg>0.f ? lg : 0.2f*lg;
            ex = expf(lg-m);
        }
        alpha[e*4+h]=ex;
        ssum += ex;
    }
    for(int mm=32;mm>=1;mm>>=1) ssum += __shfl_xor(ssum,mm);
    float inv = 1.0f/fmaxf(ssum,1e-16f);
    float acc[8];
    #pragma unroll
    for(int c=0;c<8;c++) acc[c]=0.f;
    for(int i=beg+lane;i<end;i+=64){
        int e = eids[i];
        float a = alpha[e*4+h]*inv;
        alpha[e*4+h]=a;
        if(a>0.f){
            float aw = a*w[e];
            const float* xr = xhbt + src[e]*32 + h*8;
            #pragma unroll
            for(int c=0;c<8;c++) acc[c] += aw*xr[c];
        }
    }
    for(int mm=32;mm>=1;mm>>=1){
        #pragma unroll
        for(int c=0;c<8;c++) acc[c] += __shfl_xor(acc[c],mm);
    }
    if(lane==0){
        float* o = outp + ((size_t)t*NN+n)*32 + h*8;
        #pragma unroll
        for(int c=0;c<8;c++) o[c] = acc[c] + bgat[h*8+c];
    }
}

// ---------------- K5: per-source-row normalize + dense A row write, all t ----------------
// grid (NN, 8). Builds 4 head-rows in LDS, streams out (replaces 302 MB memset+atomics).
__global__ void __launch_bounds__(256) k_scatter(const float* __restrict__ alphab,
                       const int* __restrict__ dst, float* __restrict__ attn){
    __shared__ float rowbuf[NHEAD][NN];
    __shared__ float rs[NHEAD];
    __shared__ float rsf[NHEAD];
    int n = blockIdx.x;
    int t = blockIdx.y;
    const float* alpha = alphab + (size_t)t*EE*4;
    int tid = threadIdx.x;
    for(int i=tid;i<NHEAD*NN;i+=256) ((float*)rowbuf)[i]=0.f;
    if(tid<NHEAD) rs[tid]=0.f;
    __syncthreads();
    float a=0.f; int de=0; int h=0;
    if(tid<128){
        int d = tid>>2; h = tid&3;
        int e = n*DG+d;
        a = alpha[e*4+h];
        de = dst[e];
        if(a>0.f) atomicAdd(&rs[h], a);
    }
    __syncthreads();
    if(tid<NHEAD) rsf[tid] = 1.0f/fmaxf(rs[tid],1e-9f);
    __syncthreads();
    if(tid<128 && a>0.f) atomicAdd(&rowbuf[h][de], a*rsf[h]);
    __syncthreads();
    size_t tb = (size_t)t*NHEAD*NN*NN;
    for(int i=tid;i<NHEAD*(NN/4);i+=256){
        int hh = i/(NN/4); int c4 = i%(NN/4);
        float4 v = ((const float4*)rowbuf[hh])[c4];
        ((float4*)(attn + tb + (size_t)hh*NN*NN + (size_t)n*NN))[c4] = v;
    }
}

extern "C" void kernel_launch(void* const* d_in, const int* in_sizes, int n_in,
                              void* d_out, int out_size, void* d_ws, size_t ws_size,
                              hipStream_t stream) {
    const float* Ht   = (const float*)d_in[0];
    const int*   src  = (const int*)  d_in[1];
    const int*   dst  = (const int*)  d_in[2];
    const int*   kptr = (const int*)  d_in[3];
    const float* We1  = (const float*)d_in[4];
    const float* be1  = (const float*)d_in[5];
    const float* We2  = (const float*)d_in[6];
    const float* be2  = (const float*)d_in[7];
    const float* lng  = (const float*)d_in[8];
    const float* lnb  = (const float*)d_in[9];
    const float* Wih  = (const float*)d_in[10];
    const float* Whh  = (const float*)d_in[11];
    const float* bih  = (const float*)d_in[12];
    const float* bhh  = (const float*)d_in[13];
    const float* Ws1  = (const float*)d_in[14];
    const float* bs1  = (const float*)d_in[15];
    const float* Ws2  = (const float*)d_in[16];
    const float* bs2  = (const float*)d_in[17];
    const float* Wgat = (const float*)d_in[18];
    const float* atts = (const float*)d_in[19];
    const float* attd = (const float*)d_in[20];
    const float* bgat = (const float*)d_in[21];

    float* outp = (float*)d_out;                       // (B,N,32)
    float* attn = outp + (size_t)BB*NN*32;             // (B,HEADS,N,N)

    // workspace layout (floats); total ~29 MB
    float* ws    = (float*)d_ws;
    float* GI    = ws;                    // 12288*192 = 2359296
    float* Hall  = ws + 2359296;          // 12288*64  =  786432
    float* P     = ws + 3145728;          //  786432
    float* Q     = ws + 3932160;          //  786432
    float* xh    = ws + 4718592;          //  393216
    float* as_   = ws + 5111808;          //   49152
    float* ad_   = ws + 5160960;          //   49152
    float* wbuf  = ws + 5210112;          //  393216
    float* alpha = ws + 5603328;          // 1572864
    int*   ibase = (int*)(ws + 7176192);
    int*   cursor= ibase;                 // NN
    int*   indptr= ibase + 2048;          // NN+1
    int*   eids  = ibase + 4096;          // EE

    hipMemsetAsync(cursor, 0, (size_t)NN*sizeof(int), stream);

    k_embgi<<<BB*NN/4, 256, 0, stream>>>(Ht, We1, be1, We2, be2, lng, lnb, Wih, bih, GI);
    k_count<<<EE/256, 256, 0, stream>>>(dst, cursor);
    k_scan<<<1, 256, 0, stream>>>(cursor, indptr);
    k_fill<<<EE/256, 256, 0, stream>>>(dst, cursor, eids);
    k_gru_all<<<NN/6, 384, 0, stream>>>(GI, Whh, bhh, Hall);
    k_post<<<BB*NN/4, 256, 0, stream>>>(Hall, Ws1, Wgat, atts, attd, P, Q, xh, as_, ad_);
    {
        dim3 g(NN/2, BB);
        k_edge<<<g, 64, 0, stream>>>(P, Q, bs1, Ws2, bs2, dst, kptr, wbuf);
    }
    {
        dim3 g(NN, BB);
        k_soft<<<g, 256, 0, stream>>>(indptr, eids, src, as_, ad_, wbuf, xh, bgat, alpha, outp);
        k_scatter<<<g, 256, 0, stream>>>(alpha, dst, attn);
    }
}